// Round 4
// baseline (6619.371 us; speedup 1.0000x reference)
//
#include <hip/hip_runtime.h>
#include <hip/hip_cooperative_groups.h>
#include <math.h>

namespace cg = cooperative_groups;

// ---------------------------------------------------------------- prep ------
// builds: w1t[(ky*8+kx)*3+ch][32], w2t[(ky*4+kx)*32+ci][64],
// w3t[(ky*3+kx)*64+ci][64], fcwp[(yx*64+c)][512] (undoes NCHW flatten),
// whhT[k][2048], hT0[k][b]=h0*m0 (transposed), cbuf[b][u]=c0*m0
__global__ void __launch_bounds__(256) prep_k(
    const float* __restrict__ w1, const float* __restrict__ w2,
    const float* __restrict__ w3, const float* __restrict__ fcw,
    const float* __restrict__ whh, const float* __restrict__ done,
    const float* __restrict__ h0, const float* __restrict__ c0,
    float* __restrict__ w1t, float* __restrict__ w2t, float* __restrict__ w3t,
    float* __restrict__ fcwp, float* __restrict__ whhT,
    float* __restrict__ hT0, float* __restrict__ cbuf) {
  int i = blockIdx.x * 256 + threadIdx.x;
  if (i < 6144) {
    int o = i & 31, idx = i >> 5;
    int ch = idx % 3, kyx = idx / 3;
    int ky = kyx >> 3, kx = kyx & 7;
    w1t[i] = w1[((o * 3 + ch) * 8 + ky) * 8 + kx];
    return;
  }
  i -= 6144;
  if (i < 32768) {
    int o = i & 63, idx = i >> 6;
    int ci = idx & 31, kyx = idx >> 5;
    int ky = kyx >> 2, kx = kyx & 3;
    w2t[i] = w2[((o * 32 + ci) * 4 + ky) * 4 + kx];
    return;
  }
  i -= 32768;
  if (i < 36864) {
    int o = i & 63, idx = i >> 6;
    int ci = idx & 63, kyx = idx >> 6;
    int ky = kyx / 3, kx = kyx - ky * 3;
    w3t[i] = w3[((o * 64 + ci) * 3 + ky) * 3 + kx];
    return;
  }
  i -= 36864;
  if (i < 294912) {
    int o = i & 511, r = i >> 9;
    int c = r & 63, yx = r >> 6;
    fcwp[i] = fcw[(c * 9 + yx) * 512 + o];
    return;
  }
  i -= 294912;
  if (i < 1048576) {
    int j = i & 2047, k = i >> 11;
    whhT[i] = whh[j * 512 + k];
    return;
  }
  i -= 1048576;
  if (i < 32768) {
    int b = i & 63;  // layout [k][b]
    int k = i >> 6;
    hT0[i] = h0[b * 512 + k] * (1.0f - done[b]);
    return;
  }
  i -= 32768;
  if (i < 32768) {
    int b = i >> 9;  // layout [b][u]
    cbuf[i] = c0[i] * (1.0f - done[b]);
  }
}

// ---------------------------------------------------------------- conv1 -----
// x[n][52][52][3]/255 -> a1[n][12][12][32], 8x8 stride 4, relu
__global__ void __launch_bounds__(256) conv1_k(
    const float* __restrict__ x, const float* __restrict__ w1t,
    const float* __restrict__ b1, float* __restrict__ a1) {
  __shared__ float img[8112];
  __shared__ float wt[6144];
  const int n = blockIdx.x;
  const int tid = threadIdx.x;
  const float* xp = x + (long)n * 8112;
  for (int i = tid; i < 8112; i += 256) img[i] = xp[i] * (1.0f / 255.0f);
  for (int i = tid; i < 6144; i += 256) wt[i] = w1t[i];
  __syncthreads();
  const int cq = tid & 7;   // out-channel quad: c = cq*4..cq*4+3
  const int pg = tid >> 3;  // 0..31
  const bool extra = pg < 16;
  float4 bias = *(const float4*)&b1[cq * 4];
  float4 acc[5];
  int base[5];
#pragma unroll
  for (int i = 0; i < 5; ++i) {
    acc[i] = make_float4(0.f, 0.f, 0.f, 0.f);
    int p = pg + 32 * i;
    if (p > 143) p = 143;
    int py = p / 12, px = p - py * 12;
    base[i] = py * 624 + px * 12;  // (py*4)*156 + (px*4)*3
  }
  for (int ky = 0; ky < 8; ++ky) {
    const int ib = ky * 156;
    const int wb = ky * 24 * 32;
#pragma unroll
    for (int kxc = 0; kxc < 24; ++kxc) {
      float4 w = *(const float4*)&wt[wb + kxc * 32 + cq * 4];
#pragma unroll
      for (int i = 0; i < 4; ++i) {
        float v = img[base[i] + ib + kxc];
        acc[i].x += v * w.x; acc[i].y += v * w.y;
        acc[i].z += v * w.z; acc[i].w += v * w.w;
      }
      if (extra) {
        float v = img[base[4] + ib + kxc];
        acc[4].x += v * w.x; acc[4].y += v * w.y;
        acc[4].z += v * w.z; acc[4].w += v * w.w;
      }
    }
  }
#pragma unroll
  for (int i = 0; i < 5; ++i) {
    int p = pg + 32 * i;
    if (p < 144) {
      float4 o;
      o.x = fmaxf(acc[i].x + bias.x, 0.f);
      o.y = fmaxf(acc[i].y + bias.y, 0.f);
      o.z = fmaxf(acc[i].z + bias.z, 0.f);
      o.w = fmaxf(acc[i].w + bias.w, 0.f);
      *(float4*)&a1[(long)n * 4608 + p * 32 + cq * 4] = o;
    }
  }
}

// ---------------------------------------------------------------- conv2 -----
// a1[n][12][12][32] -> a2[n][5][5][64], 4x4 stride 2, relu; 2 images/block
__global__ void __launch_bounds__(256) conv2_k(
    const float* __restrict__ a1, const float* __restrict__ w2t,
    const float* __restrict__ b2, float* __restrict__ a2) {
  __shared__ float img[9216];
  __shared__ float wt[4096];
  const int n0 = blockIdx.x * 2;
  const int tid = threadIdx.x;
  const float* ip = a1 + (long)n0 * 4608;
  for (int i = tid; i < 9216; i += 256) img[i] = ip[i];
  const int cq = tid & 15;  // c = cq*4..+3 of 64
  const int pg = tid >> 4;  // 0..15
  float4 bias = *(const float4*)&b2[cq * 4];
  float4 acc[4];
  int pbase[4], pout[4];
  bool pval[4];
#pragma unroll
  for (int i = 0; i < 4; ++i) {
    acc[i] = make_float4(0.f, 0.f, 0.f, 0.f);
    int pu = pg + 16 * i;
    pval[i] = pu < 50;
    if (pu > 49) pu = 49;
    int sel = pu / 25, p = pu - sel * 25;
    int py = p / 5, px = p - py * 5;
    pbase[i] = sel * 4608 + (py * 24 + px * 2) * 32;
    pout[i] = (n0 + sel) * 1600 + p * 64;
  }
  for (int ch = 0; ch < 8; ++ch) {
    __syncthreads();
#pragma unroll
    for (int q = 0; q < 4; ++q) {
      int f4i = tid + 256 * q;
      *(float4*)&wt[f4i * 4] = *(const float4*)&w2t[ch * 4096 + f4i * 4];
    }
    __syncthreads();
    for (int il = 0; il < 64; ++il) {
      int idx = ch * 64 + il;
      int ci = idx & 31;
      int kyx = idx >> 5;
      int ky = kyx >> 2, kx = kyx & 3;
      int ioff = (ky * 12 + kx) * 32 + ci;
      float4 w = *(const float4*)&wt[il * 64 + cq * 4];
#pragma unroll
      for (int i = 0; i < 4; ++i) {
        if (pval[i]) {
          float v = img[pbase[i] + ioff];
          acc[i].x += v * w.x; acc[i].y += v * w.y;
          acc[i].z += v * w.z; acc[i].w += v * w.w;
        }
      }
    }
  }
#pragma unroll
  for (int i = 0; i < 4; ++i) {
    if (pval[i]) {
      float4 o;
      o.x = fmaxf(acc[i].x + bias.x, 0.f);
      o.y = fmaxf(acc[i].y + bias.y, 0.f);
      o.z = fmaxf(acc[i].z + bias.z, 0.f);
      o.w = fmaxf(acc[i].w + bias.w, 0.f);
      *(float4*)&a2[(long)pout[i] + cq * 4] = o;
    }
  }
}

// ---------------------------------------------------------------- conv3 -----
// a2[n][5][5][64] -> a3[n][3][3][64] (NHWC flat), 3x3 stride 1, relu; 4 img/blk
__global__ void __launch_bounds__(256) conv3_k(
    const float* __restrict__ a2, const float* __restrict__ w3t,
    const float* __restrict__ b3, float* __restrict__ a3) {
  __shared__ float img[6400];
  __shared__ float wt[9216];
  const int n0 = blockIdx.x * 4;
  const int tid = threadIdx.x;
  const float* ip = a2 + (long)n0 * 1600;
  for (int i = tid; i < 6400; i += 256) img[i] = ip[i];
  const int cq = tid & 15;
  const int pg = tid >> 4;
  float4 bias = *(const float4*)&b3[cq * 4];
  float4 acc[3];
  int pbase[3], pout[3];
  bool pval[3];
#pragma unroll
  for (int i = 0; i < 3; ++i) {
    acc[i] = make_float4(0.f, 0.f, 0.f, 0.f);
    int pu = pg + 16 * i;
    pval[i] = pu < 36;
    if (pu > 35) pu = 35;
    int sel = pu / 9, p = pu - sel * 9;
    int py = p / 3, px = p - py * 3;
    pbase[i] = sel * 1600 + (py * 5 + px) * 64;
    pout[i] = (n0 + sel) * 576 + p * 64;
  }
  for (int ch = 0; ch < 4; ++ch) {
    __syncthreads();
#pragma unroll
    for (int q = 0; q < 9; ++q) {
      int f4i = tid + 256 * q;
      *(float4*)&wt[f4i * 4] = *(const float4*)&w3t[ch * 9216 + f4i * 4];
    }
    __syncthreads();
    for (int il = 0; il < 144; ++il) {
      int idx = ch * 144 + il;
      int ci = idx & 63;
      int kyx = idx >> 6;
      int ky = kyx / 3, kx = kyx - ky * 3;
      int ioff = (ky * 5 + kx) * 64 + ci;
      float4 w = *(const float4*)&wt[il * 64 + cq * 4];
#pragma unroll
      for (int i = 0; i < 3; ++i) {
        if (pval[i]) {
          float v = img[pbase[i] + ioff];
          acc[i].x += v * w.x; acc[i].y += v * w.y;
          acc[i].z += v * w.z; acc[i].w += v * w.w;
        }
      }
    }
  }
#pragma unroll
  for (int i = 0; i < 3; ++i) {
    if (pval[i]) {
      float4 o;
      o.x = fmaxf(acc[i].x + bias.x, 0.f);
      o.y = fmaxf(acc[i].y + bias.y, 0.f);
      o.z = fmaxf(acc[i].z + bias.z, 0.f);
      o.w = fmaxf(acc[i].w + bias.w, 0.f);
      *(float4*)&a3[(long)pout[i] + cq * 4] = o;
    }
  }
}

// ---------------------------------------------------------------- gemm ------
// C[M][N] = A[M][K] * B (+bias, opt relu). NT=0: B[K][N]; NT=1: B[N][K].
// 64x64 tile, BK=32, 256 threads, 4x4 microtile.
__global__ void __launch_bounds__(256) gemm_k(
    const float* __restrict__ A, const float* __restrict__ B,
    const float* __restrict__ bias, float* __restrict__ C,
    const int K, const int N, const int NT, const int RELU) {
  __shared__ float As[32][68];
  __shared__ float Bs[32][68];
  const int tid = threadIdx.x;
  const int bm = blockIdx.x * 64;
  const int bn = blockIdx.y * 64;
  const int tx = tid & 15, ty = tid >> 4;
  float acc[4][4] = {{0.f}};
  for (int k0 = 0; k0 < K; k0 += 32) {
#pragma unroll
    for (int q = 0; q < 2; ++q) {
      int qi = tid * 2 + q;
      int m = qi >> 3, kc = (qi & 7) << 2;
      float4 v = *(const float4*)&A[(long)(bm + m) * K + k0 + kc];
      As[kc][m] = v.x; As[kc + 1][m] = v.y; As[kc + 2][m] = v.z; As[kc + 3][m] = v.w;
    }
    if (NT) {
#pragma unroll
      for (int q = 0; q < 2; ++q) {
        int qi = tid * 2 + q;
        int nn = qi >> 3, kc = (qi & 7) << 2;
        float4 v = *(const float4*)&B[(long)(bn + nn) * K + k0 + kc];
        Bs[kc][nn] = v.x; Bs[kc + 1][nn] = v.y; Bs[kc + 2][nn] = v.z; Bs[kc + 3][nn] = v.w;
      }
    } else {
#pragma unroll
      for (int q = 0; q < 2; ++q) {
        int qi = tid * 2 + q;
        int kr = qi >> 4, nc = (qi & 15) << 2;
        *(float4*)&Bs[kr][nc] = *(const float4*)&B[(long)(k0 + kr) * N + bn + nc];
      }
    }
    __syncthreads();
#pragma unroll 8
    for (int kk = 0; kk < 32; ++kk) {
      float4 av = *(const float4*)&As[kk][ty << 2];
      float4 bv = *(const float4*)&Bs[kk][tx << 2];
      acc[0][0] += av.x * bv.x; acc[0][1] += av.x * bv.y; acc[0][2] += av.x * bv.z; acc[0][3] += av.x * bv.w;
      acc[1][0] += av.y * bv.x; acc[1][1] += av.y * bv.y; acc[1][2] += av.y * bv.z; acc[1][3] += av.y * bv.w;
      acc[2][0] += av.z * bv.x; acc[2][1] += av.z * bv.y; acc[2][2] += av.z * bv.z; acc[2][3] += av.z * bv.w;
      acc[3][0] += av.w * bv.x; acc[3][1] += av.w * bv.y; acc[3][2] += av.w * bv.z; acc[3][3] += av.w * bv.w;
    }
    __syncthreads();
  }
  float4 bv = *(const float4*)&bias[bn + (tx << 2)];
#pragma unroll
  for (int r = 0; r < 4; ++r) {
    int m = bm + (ty << 2) + r;
    float4 o;
    o.x = acc[r][0] + bv.x; o.y = acc[r][1] + bv.y;
    o.z = acc[r][2] + bv.z; o.w = acc[r][3] + bv.w;
    if (RELU) {
      o.x = fmaxf(o.x, 0.f); o.y = fmaxf(o.y, 0.f);
      o.z = fmaxf(o.z, 0.f); o.w = fmaxf(o.w, 0.f);
    }
    *(float4*)&C[(long)m * N + bn + (tx << 2)] = o;
  }
}

// ---------------------------------------------------------------- lstm ------
// Round-0's verified dataflow, unchanged except the block->(uslice,bg) map.
// XCD-affinity swizzle: with round-robin dispatch, XCD x hosts bids == x (mod 8).
// uslice = (bid&7)*4 + (bid>>6) gives each XCD 4 consecutive u-slices -> its
// weight working set is 4 x 512KB = 2MB (one 64B line per gate per k-row),
// L2-resident across all 128 steps instead of re-fetching 4MB/step from HBM.
// bg = (bid>>3)&7. Bijective over 256 blocks.
__global__ void __launch_bounds__(256) lstm_k(
    const float* __restrict__ gx, const float* __restrict__ whhT,
    const float* __restrict__ done, float* __restrict__ hT2,
    float* __restrict__ cbuf, float* __restrict__ hseq,
    float* __restrict__ outh, float* __restrict__ outc) {
  __shared__ float red[256][37];
  cg::grid_group grid = cg::this_grid();
  const int tid = threadIdx.x;
  const int bid = blockIdx.x;
  const int uslice = (bid & 7) * 4 + (bid >> 6);  // 0..31 (XCD-affine)
  const int bg = (bid >> 3) & 7;                  // 0..7
  const int uu = tid & 15;
  const int kc = tid >> 4;
  const int u = uslice * 16 + uu;
  const int b0 = bg * 8;
  const int fbl = tid >> 4;

  for (int t = 0; t < 128; ++t) {
    const float* hTp = hT2 + (t & 1) * 32768;
    float a0[8] = {0.f}, a1_[8] = {0.f}, a2_[8] = {0.f}, a3_[8] = {0.f};
    const int kbeg = kc * 32;
#pragma unroll 4
    for (int kk = 0; kk < 32; ++kk) {
      int k = kbeg + kk;
      const float* wr = whhT + k * 2048;
      float w0 = wr[u];
      float w1 = wr[u + 512];
      float w2 = wr[u + 1024];
      float w3 = wr[u + 1536];
      float hv[8];
      *(float4*)&hv[0] = *(const float4*)&hTp[k * 64 + b0];
      *(float4*)&hv[4] = *(const float4*)&hTp[k * 64 + b0 + 4];
#pragma unroll
      for (int j = 0; j < 8; ++j) {
        a0[j] += w0 * hv[j]; a1_[j] += w1 * hv[j];
        a2_[j] += w2 * hv[j]; a3_[j] += w3 * hv[j];
      }
    }
#pragma unroll
    for (int j = 0; j < 8; ++j) {
      red[tid][j] = a0[j];       red[tid][8 + j] = a1_[j];
      red[tid][16 + j] = a2_[j]; red[tid][24 + j] = a3_[j];
    }
    __syncthreads();
    if (fbl < 8) {
      float s0 = 0.f, s1 = 0.f, s2 = 0.f, s3 = 0.f;
#pragma unroll
      for (int q = 0; q < 16; ++q) {
        const float* rp = red[q * 16 + uu];
        s0 += rp[fbl]; s1 += rp[8 + fbl]; s2 += rp[16 + fbl]; s3 += rp[24 + fbl];
      }
      const int b = b0 + fbl;
      const int ug = uslice * 16 + uu;
      const int row = t * 64 + b;
      const float* gxr = gx + (long)row * 2048;
      float pi = s0 + gxr[ug];
      float pf = s1 + gxr[512 + ug];
      float pg_ = s2 + gxr[1024 + ug];
      float po = s3 + gxr[1536 + ug];
      float ig = 1.f / (1.f + expf(-pi));
      float fg = 1.f / (1.f + expf(-pf));
      float og = 1.f / (1.f + expf(-po));
      float gg = tanhf(pg_);
      float cn = fg * cbuf[b * 512 + ug] + ig * gg;
      float hn = og * tanhf(cn);
      hseq[(long)row * 512 + ug] = hn;
      if (t == 127) {
        outh[b * 512 + ug] = hn;
        outc[b * 512 + ug] = cn;
      } else {
        float mn = 1.f - done[(t + 1) * 64 + b];
        cbuf[b * 512 + ug] = cn * mn;
        hT2[((t + 1) & 1) * 32768 + ug * 64 + b] = hn * mn;
      }
    }
    grid.sync();
  }
}

// ---------------------------------------------------------------- heads -----
// one wave per row; lanes: j=lane&15 (0..14 logits, 15 critic), kc=lane>>4.
__global__ void __launch_bounds__(256) heads_k(
    const float* __restrict__ hseq, const float* __restrict__ aw,
    const float* __restrict__ ab, const float* __restrict__ cw,
    const float* __restrict__ cb, const int* __restrict__ action,
    float* __restrict__ out) {
  const int lane = threadIdx.x & 63;
  const int wid = threadIdx.x >> 6;
  const int row = blockIdx.x * 4 + wid;
  const int j = lane & 15;
  const int kc = lane >> 4;
  const float* f = hseq + (long)row * 512;
  float acc = 0.f;
  if (j < 15) {
    for (int k = kc * 128; k < kc * 128 + 128; ++k) acc += f[k] * aw[k * 15 + j];
  } else {
    for (int k = kc * 128; k < kc * 128 + 128; ++k) acc += f[k] * cw[k];
  }
  acc += __shfl_xor(acc, 16);
  acc += __shfl_xor(acc, 32);
  float logit = (j < 15) ? acc + ab[j] : -1e30f;
  float m = logit;
#pragma unroll
  for (int off = 1; off < 16; off <<= 1) m = fmaxf(m, __shfl_xor(m, off));
  float p = (j < 15) ? expf(logit - m) : 0.f;
  float S = p;
#pragma unroll
  for (int off = 1; off < 16; off <<= 1) S += __shfl_xor(S, off);
  float logS = logf(S);
  float lp = logit - m - logS;
  float e = (j < 15) ? p * lp : 0.f;
  float es = e;
#pragma unroll
  for (int off = 1; off < 16; off <<= 1) es += __shfl_xor(es, off);
  float ent = -es / S;
  int a = action[row];
  float lpa = __shfl(lp, (lane & 48) | a);
  float val = __shfl(acc, (lane & 48) | 15) + cb[0];
  if (lane == 0) {
    out[row] = lpa;
    out[8192 + row] = ent;
    out[16384 + row] = val;
  }
}

// ---------------------------------------------------------------- host ------
extern "C" void kernel_launch(void* const* d_in, const int* in_sizes, int n_in,
                              void* d_out, int out_size, void* d_ws, size_t ws_size,
                              hipStream_t stream) {
  const float* x    = (const float*)d_in[0];
  const float* done = (const float*)d_in[1];
  const float* h0   = (const float*)d_in[2];
  const float* c0   = (const float*)d_in[3];
  const int*   act  = (const int*)d_in[4];
  const float* w1   = (const float*)d_in[5];
  const float* b1   = (const float*)d_in[6];
  const float* w2   = (const float*)d_in[7];
  const float* b2   = (const float*)d_in[8];
  const float* w3   = (const float*)d_in[9];
  const float* b3   = (const float*)d_in[10];
  const float* fcw  = (const float*)d_in[11];
  const float* fcb  = (const float*)d_in[12];
  const float* wih  = (const float*)d_in[13];
  const float* whh  = (const float*)d_in[14];
  const float* blst = (const float*)d_in[15];
  const float* aw   = (const float*)d_in[16];
  const float* ab   = (const float*)d_in[17];
  const float* cw   = (const float*)d_in[18];
  const float* cb   = (const float*)d_in[19];
  float* ws  = (float*)d_ws;
  float* out = (float*)d_out;

  // ws layout (floats); a3/hid/hseq reuse a1's region after a1 is dead.
  float* a1   = ws;                  // 37748736
  float* a3   = ws;                  //  4718592 (reuses a1)
  float* hid  = ws + 4718592;        //  4194304 (reuses a1)
  float* hseq = ws + 8912896;        //  4194304 (reuses a1)
  float* a2   = ws + 37748736;       // 13107200
  float* gxb  = ws + 50855936;       // 16777216
  float* w1t  = ws + 67633152;       //     6144
  float* w2t  = ws + 67639296;       //    32768
  float* w3t  = ws + 67672064;       //    36864
  float* fcwp = ws + 67708928;       //   294912
  float* whhT = ws + 68003840;       //  1048576
  float* hT2  = ws + 69052416;       //    65536 (double-buffered [2][512][64])
  float* cbuf = ws + 69117952;       //    32768  -> total 69150720 f = 277 MB

  hipLaunchKernelGGL(prep_k, dim3(5800), dim3(256), 0, stream,
                     w1, w2, w3, fcw, whh, done, h0, c0,
                     w1t, w2t, w3t, fcwp, whhT, hT2, cbuf);
  hipLaunchKernelGGL(conv1_k, dim3(8192), dim3(256), 0, stream, x, w1t, b1, a1);
  hipLaunchKernelGGL(conv2_k, dim3(4096), dim3(256), 0, stream, a1, w2t, b2, a2);
  hipLaunchKernelGGL(conv3_k, dim3(2048), dim3(256), 0, stream, a2, w3t, b3, a3);
  hipLaunchKernelGGL(gemm_k, dim3(128, 8), dim3(256), 0, stream,
                     a3, fcwp, fcb, hid, 576, 512, 0, 1);
  hipLaunchKernelGGL(gemm_k, dim3(128, 32), dim3(256), 0, stream,
                     hid, wih, blst, gxb, 512, 2048, 1, 0);
  {
    const float* gxp = gxb; const float* whhTp = whhT; const float* dp = done;
    float* hT2p = hT2; float* cbp = cbuf; float* hsp = hseq;
    float* ohp = out + 24576; float* ocp = out + 57344;
    void* args[] = {(void*)&gxp, (void*)&whhTp, (void*)&dp, (void*)&hT2p,
                    (void*)&cbp, (void*)&hsp, (void*)&ohp, (void*)&ocp};
    hipLaunchCooperativeKernel((void*)lstm_k, dim3(256), dim3(256), args, 0, stream);
  }
  hipLaunchKernelGGL(heads_k, dim3(2048), dim3(256), 0, stream,
                     hseq, aw, ab, cw, cb, act, out);
}

// Round 5
// 2717.555 us; speedup vs baseline: 2.4358x; 2.4358x over previous
//
#include <hip/hip_runtime.h>
#include <math.h>

// ---------------------------------------------------------------- prep ------
// builds: w1t[(ky*8+kx)*3+ch][32], w2t[(ky*4+kx)*32+ci][64],
// w3t[(ky*3+kx)*64+ci][64], fcwp[(yx*64+c)][512] (undoes NCHW flatten),
// whhT[k][2048], hT0[k][b]=h0*m0 (transposed), cbuf[b][u]=c0*m0
__global__ void __launch_bounds__(256) prep_k(
    const float* __restrict__ w1, const float* __restrict__ w2,
    const float* __restrict__ w3, const float* __restrict__ fcw,
    const float* __restrict__ whh, const float* __restrict__ done,
    const float* __restrict__ h0, const float* __restrict__ c0,
    float* __restrict__ w1t, float* __restrict__ w2t, float* __restrict__ w3t,
    float* __restrict__ fcwp, float* __restrict__ whhT,
    float* __restrict__ hT0, float* __restrict__ cbuf) {
  int i = blockIdx.x * 256 + threadIdx.x;
  if (i < 6144) {
    int o = i & 31, idx = i >> 5;
    int ch = idx % 3, kyx = idx / 3;
    int ky = kyx >> 3, kx = kyx & 7;
    w1t[i] = w1[((o * 3 + ch) * 8 + ky) * 8 + kx];
    return;
  }
  i -= 6144;
  if (i < 32768) {
    int o = i & 63, idx = i >> 6;
    int ci = idx & 31, kyx = idx >> 5;
    int ky = kyx >> 2, kx = kyx & 3;
    w2t[i] = w2[((o * 32 + ci) * 4 + ky) * 4 + kx];
    return;
  }
  i -= 32768;
  if (i < 36864) {
    int o = i & 63, idx = i >> 6;
    int ci = idx & 63, kyx = idx >> 6;
    int ky = kyx / 3, kx = kyx - ky * 3;
    w3t[i] = w3[((o * 64 + ci) * 3 + ky) * 3 + kx];
    return;
  }
  i -= 36864;
  if (i < 294912) {
    int o = i & 511, r = i >> 9;
    int c = r & 63, yx = r >> 6;
    fcwp[i] = fcw[(c * 9 + yx) * 512 + o];
    return;
  }
  i -= 294912;
  if (i < 1048576) {
    int j = i & 2047, k = i >> 11;
    whhT[i] = whh[j * 512 + k];
    return;
  }
  i -= 1048576;
  if (i < 32768) {
    int b = i & 63;  // layout [k][b]
    int k = i >> 6;
    hT0[i] = h0[b * 512 + k] * (1.0f - done[b]);
    return;
  }
  i -= 32768;
  if (i < 32768) {
    int b = i >> 9;  // layout [b][u]
    cbuf[i] = c0[i] * (1.0f - done[b]);
  }
}

// ---------------------------------------------------------------- conv1 -----
// x[n][52][52][3]/255 -> a1[n][12][12][32], 8x8 stride 4, relu
__global__ void __launch_bounds__(256) conv1_k(
    const float* __restrict__ x, const float* __restrict__ w1t,
    const float* __restrict__ b1, float* __restrict__ a1) {
  __shared__ float img[8112];
  __shared__ float wt[6144];
  const int n = blockIdx.x;
  const int tid = threadIdx.x;
  const float* xp = x + (long)n * 8112;
  for (int i = tid; i < 8112; i += 256) img[i] = xp[i] * (1.0f / 255.0f);
  for (int i = tid; i < 6144; i += 256) wt[i] = w1t[i];
  __syncthreads();
  const int cq = tid & 7;   // out-channel quad: c = cq*4..cq*4+3
  const int pg = tid >> 3;  // 0..31
  const bool extra = pg < 16;
  float4 bias = *(const float4*)&b1[cq * 4];
  float4 acc[5];
  int base[5];
#pragma unroll
  for (int i = 0; i < 5; ++i) {
    acc[i] = make_float4(0.f, 0.f, 0.f, 0.f);
    int p = pg + 32 * i;
    if (p > 143) p = 143;
    int py = p / 12, px = p - py * 12;
    base[i] = py * 624 + px * 12;  // (py*4)*156 + (px*4)*3
  }
  for (int ky = 0; ky < 8; ++ky) {
    const int ib = ky * 156;
    const int wb = ky * 24 * 32;
#pragma unroll
    for (int kxc = 0; kxc < 24; ++kxc) {
      float4 w = *(const float4*)&wt[wb + kxc * 32 + cq * 4];
#pragma unroll
      for (int i = 0; i < 4; ++i) {
        float v = img[base[i] + ib + kxc];
        acc[i].x += v * w.x; acc[i].y += v * w.y;
        acc[i].z += v * w.z; acc[i].w += v * w.w;
      }
      if (extra) {
        float v = img[base[4] + ib + kxc];
        acc[4].x += v * w.x; acc[4].y += v * w.y;
        acc[4].z += v * w.z; acc[4].w += v * w.w;
      }
    }
  }
#pragma unroll
  for (int i = 0; i < 5; ++i) {
    int p = pg + 32 * i;
    if (p < 144) {
      float4 o;
      o.x = fmaxf(acc[i].x + bias.x, 0.f);
      o.y = fmaxf(acc[i].y + bias.y, 0.f);
      o.z = fmaxf(acc[i].z + bias.z, 0.f);
      o.w = fmaxf(acc[i].w + bias.w, 0.f);
      *(float4*)&a1[(long)n * 4608 + p * 32 + cq * 4] = o;
    }
  }
}

// ---------------------------------------------------------------- conv2 -----
// a1[n][12][12][32] -> a2[n][5][5][64], 4x4 stride 2, relu; 2 images/block
__global__ void __launch_bounds__(256) conv2_k(
    const float* __restrict__ a1, const float* __restrict__ w2t,
    const float* __restrict__ b2, float* __restrict__ a2) {
  __shared__ float img[9216];
  __shared__ float wt[4096];
  const int n0 = blockIdx.x * 2;
  const int tid = threadIdx.x;
  const float* ip = a1 + (long)n0 * 4608;
  for (int i = tid; i < 9216; i += 256) img[i] = ip[i];
  const int cq = tid & 15;  // c = cq*4..+3 of 64
  const int pg = tid >> 4;  // 0..15
  float4 bias = *(const float4*)&b2[cq * 4];
  float4 acc[4];
  int pbase[4], pout[4];
  bool pval[4];
#pragma unroll
  for (int i = 0; i < 4; ++i) {
    acc[i] = make_float4(0.f, 0.f, 0.f, 0.f);
    int pu = pg + 16 * i;
    pval[i] = pu < 50;
    if (pu > 49) pu = 49;
    int sel = pu / 25, p = pu - sel * 25;
    int py = p / 5, px = p - py * 5;
    pbase[i] = sel * 4608 + (py * 24 + px * 2) * 32;
    pout[i] = (n0 + sel) * 1600 + p * 64;
  }
  for (int ch = 0; ch < 8; ++ch) {
    __syncthreads();
#pragma unroll
    for (int q = 0; q < 4; ++q) {
      int f4i = tid + 256 * q;
      *(float4*)&wt[f4i * 4] = *(const float4*)&w2t[ch * 4096 + f4i * 4];
    }
    __syncthreads();
    for (int il = 0; il < 64; ++il) {
      int idx = ch * 64 + il;
      int ci = idx & 31;
      int kyx = idx >> 5;
      int ky = kyx >> 2, kx = kyx & 3;
      int ioff = (ky * 12 + kx) * 32 + ci;
      float4 w = *(const float4*)&wt[il * 64 + cq * 4];
#pragma unroll
      for (int i = 0; i < 4; ++i) {
        if (pval[i]) {
          float v = img[pbase[i] + ioff];
          acc[i].x += v * w.x; acc[i].y += v * w.y;
          acc[i].z += v * w.z; acc[i].w += v * w.w;
        }
      }
    }
  }
#pragma unroll
  for (int i = 0; i < 4; ++i) {
    if (pval[i]) {
      float4 o;
      o.x = fmaxf(acc[i].x + bias.x, 0.f);
      o.y = fmaxf(acc[i].y + bias.y, 0.f);
      o.z = fmaxf(acc[i].z + bias.z, 0.f);
      o.w = fmaxf(acc[i].w + bias.w, 0.f);
      *(float4*)&a2[(long)pout[i] + cq * 4] = o;
    }
  }
}

// ---------------------------------------------------------------- conv3 -----
// a2[n][5][5][64] -> a3[n][3][3][64] (NHWC flat), 3x3 stride 1, relu; 4 img/blk
__global__ void __launch_bounds__(256) conv3_k(
    const float* __restrict__ a2, const float* __restrict__ w3t,
    const float* __restrict__ b3, float* __restrict__ a3) {
  __shared__ float img[6400];
  __shared__ float wt[9216];
  const int n0 = blockIdx.x * 4;
  const int tid = threadIdx.x;
  const float* ip = a2 + (long)n0 * 1600;
  for (int i = tid; i < 6400; i += 256) img[i] = ip[i];
  const int cq = tid & 15;
  const int pg = tid >> 4;
  float4 bias = *(const float4*)&b3[cq * 4];
  float4 acc[3];
  int pbase[3], pout[3];
  bool pval[3];
#pragma unroll
  for (int i = 0; i < 3; ++i) {
    acc[i] = make_float4(0.f, 0.f, 0.f, 0.f);
    int pu = pg + 16 * i;
    pval[i] = pu < 36;
    if (pu > 35) pu = 35;
    int sel = pu / 9, p = pu - sel * 9;
    int py = p / 3, px = p - py * 3;
    pbase[i] = sel * 1600 + (py * 5 + px) * 64;
    pout[i] = (n0 + sel) * 576 + p * 64;
  }
  for (int ch = 0; ch < 4; ++ch) {
    __syncthreads();
#pragma unroll
    for (int q = 0; q < 9; ++q) {
      int f4i = tid + 256 * q;
      *(float4*)&wt[f4i * 4] = *(const float4*)&w3t[ch * 9216 + f4i * 4];
    }
    __syncthreads();
    for (int il = 0; il < 144; ++il) {
      int idx = ch * 144 + il;
      int ci = idx & 63;
      int kyx = idx >> 6;
      int ky = kyx / 3, kx = kyx - ky * 3;
      int ioff = (ky * 5 + kx) * 64 + ci;
      float4 w = *(const float4*)&wt[il * 64 + cq * 4];
#pragma unroll
      for (int i = 0; i < 3; ++i) {
        if (pval[i]) {
          float v = img[pbase[i] + ioff];
          acc[i].x += v * w.x; acc[i].y += v * w.y;
          acc[i].z += v * w.z; acc[i].w += v * w.w;
        }
      }
    }
  }
#pragma unroll
  for (int i = 0; i < 3; ++i) {
    if (pval[i]) {
      float4 o;
      o.x = fmaxf(acc[i].x + bias.x, 0.f);
      o.y = fmaxf(acc[i].y + bias.y, 0.f);
      o.z = fmaxf(acc[i].z + bias.z, 0.f);
      o.w = fmaxf(acc[i].w + bias.w, 0.f);
      *(float4*)&a3[(long)pout[i] + cq * 4] = o;
    }
  }
}

// ---------------------------------------------------------------- gemm ------
// C[M][N] = A[M][K] * B (+bias, opt relu). NT=0: B[K][N]; NT=1: B[N][K].
// 64x64 tile, BK=32, 256 threads, 4x4 microtile.
__global__ void __launch_bounds__(256) gemm_k(
    const float* __restrict__ A, const float* __restrict__ B,
    const float* __restrict__ bias, float* __restrict__ C,
    const int K, const int N, const int NT, const int RELU) {
  __shared__ float As[32][68];
  __shared__ float Bs[32][68];
  const int tid = threadIdx.x;
  const int bm = blockIdx.x * 64;
  const int bn = blockIdx.y * 64;
  const int tx = tid & 15, ty = tid >> 4;
  float acc[4][4] = {{0.f}};
  for (int k0 = 0; k0 < K; k0 += 32) {
#pragma unroll
    for (int q = 0; q < 2; ++q) {
      int qi = tid * 2 + q;
      int m = qi >> 3, kc = (qi & 7) << 2;
      float4 v = *(const float4*)&A[(long)(bm + m) * K + k0 + kc];
      As[kc][m] = v.x; As[kc + 1][m] = v.y; As[kc + 2][m] = v.z; As[kc + 3][m] = v.w;
    }
    if (NT) {
#pragma unroll
      for (int q = 0; q < 2; ++q) {
        int qi = tid * 2 + q;
        int nn = qi >> 3, kc = (qi & 7) << 2;
        float4 v = *(const float4*)&B[(long)(bn + nn) * K + k0 + kc];
        Bs[kc][nn] = v.x; Bs[kc + 1][nn] = v.y; Bs[kc + 2][nn] = v.z; Bs[kc + 3][nn] = v.w;
      }
    } else {
#pragma unroll
      for (int q = 0; q < 2; ++q) {
        int qi = tid * 2 + q;
        int kr = qi >> 4, nc = (qi & 15) << 2;
        *(float4*)&Bs[kr][nc] = *(const float4*)&B[(long)(k0 + kr) * N + bn + nc];
      }
    }
    __syncthreads();
#pragma unroll 8
    for (int kk = 0; kk < 32; ++kk) {
      float4 av = *(const float4*)&As[kk][ty << 2];
      float4 bv = *(const float4*)&Bs[kk][tx << 2];
      acc[0][0] += av.x * bv.x; acc[0][1] += av.x * bv.y; acc[0][2] += av.x * bv.z; acc[0][3] += av.x * bv.w;
      acc[1][0] += av.y * bv.x; acc[1][1] += av.y * bv.y; acc[1][2] += av.y * bv.z; acc[1][3] += av.y * bv.w;
      acc[2][0] += av.z * bv.x; acc[2][1] += av.z * bv.y; acc[2][2] += av.z * bv.z; acc[2][3] += av.z * bv.w;
      acc[3][0] += av.w * bv.x; acc[3][1] += av.w * bv.y; acc[3][2] += av.w * bv.z; acc[3][3] += av.w * bv.w;
    }
    __syncthreads();
  }
  float4 bv = *(const float4*)&bias[bn + (tx << 2)];
#pragma unroll
  for (int r = 0; r < 4; ++r) {
    int m = bm + (ty << 2) + r;
    float4 o;
    o.x = acc[r][0] + bv.x; o.y = acc[r][1] + bv.y;
    o.z = acc[r][2] + bv.z; o.w = acc[r][3] + bv.w;
    if (RELU) {
      o.x = fmaxf(o.x, 0.f); o.y = fmaxf(o.y, 0.f);
      o.z = fmaxf(o.z, 0.f); o.w = fmaxf(o.w, 0.f);
    }
    *(float4*)&C[(long)m * N + bn + (tx << 2)] = o;
  }
}

// ------------------------------------------------------------- lstm step ----
// ONE timestep per launch; kernel boundary provides cross-XCD visibility
// (replaces grid.sync, which dominated the cooperative version at ~32us/step).
// Body is byte-identical to the round-4 verified step; t is an argument.
// XCD-affinity swizzle keeps each XCD's 2MB weight slice L2-resident across
// launches (clean lines survive kernel boundaries).
__global__ void __launch_bounds__(256) lstm_step_k(
    const float* __restrict__ gx, const float* __restrict__ whhT,
    const float* __restrict__ done, float* __restrict__ hT2,
    float* __restrict__ cbuf, float* __restrict__ hseq,
    float* __restrict__ outh, float* __restrict__ outc, const int t) {
  __shared__ float red[256][37];
  const int tid = threadIdx.x;
  const int bid = blockIdx.x;
  const int uslice = (bid & 7) * 4 + (bid >> 6);  // 0..31 (XCD-affine)
  const int bg = (bid >> 3) & 7;                  // 0..7
  const int uu = tid & 15;
  const int kc = tid >> 4;
  const int u = uslice * 16 + uu;
  const int b0 = bg * 8;
  const int fbl = tid >> 4;

  const float* hTp = hT2 + (t & 1) * 32768;
  float a0[8] = {0.f}, a1_[8] = {0.f}, a2_[8] = {0.f}, a3_[8] = {0.f};
  const int kbeg = kc * 32;
#pragma unroll 4
  for (int kk = 0; kk < 32; ++kk) {
    int k = kbeg + kk;
    const float* wr = whhT + k * 2048;
    float w0 = wr[u];
    float w1 = wr[u + 512];
    float w2 = wr[u + 1024];
    float w3 = wr[u + 1536];
    float hv[8];
    *(float4*)&hv[0] = *(const float4*)&hTp[k * 64 + b0];
    *(float4*)&hv[4] = *(const float4*)&hTp[k * 64 + b0 + 4];
#pragma unroll
    for (int j = 0; j < 8; ++j) {
      a0[j] += w0 * hv[j]; a1_[j] += w1 * hv[j];
      a2_[j] += w2 * hv[j]; a3_[j] += w3 * hv[j];
    }
  }
#pragma unroll
  for (int j = 0; j < 8; ++j) {
    red[tid][j] = a0[j];       red[tid][8 + j] = a1_[j];
    red[tid][16 + j] = a2_[j]; red[tid][24 + j] = a3_[j];
  }
  __syncthreads();
  if (fbl < 8) {
    float s0 = 0.f, s1 = 0.f, s2 = 0.f, s3 = 0.f;
#pragma unroll
    for (int q = 0; q < 16; ++q) {
      const float* rp = red[q * 16 + uu];
      s0 += rp[fbl]; s1 += rp[8 + fbl]; s2 += rp[16 + fbl]; s3 += rp[24 + fbl];
    }
    const int b = b0 + fbl;
    const int ug = uslice * 16 + uu;
    const int row = t * 64 + b;
    const float* gxr = gx + (long)row * 2048;
    float pi = s0 + gxr[ug];
    float pf = s1 + gxr[512 + ug];
    float pg_ = s2 + gxr[1024 + ug];
    float po = s3 + gxr[1536 + ug];
    float ig = 1.f / (1.f + expf(-pi));
    float fg = 1.f / (1.f + expf(-pf));
    float og = 1.f / (1.f + expf(-po));
    float gg = tanhf(pg_);
    float cn = fg * cbuf[b * 512 + ug] + ig * gg;
    float hn = og * tanhf(cn);
    hseq[(long)row * 512 + ug] = hn;
    if (t == 127) {
      outh[b * 512 + ug] = hn;
      outc[b * 512 + ug] = cn;
    } else {
      float mn = 1.f - done[(t + 1) * 64 + b];
      cbuf[b * 512 + ug] = cn * mn;
      hT2[((t + 1) & 1) * 32768 + ug * 64 + b] = hn * mn;
    }
  }
}

// ---------------------------------------------------------------- heads -----
// one wave per row; lanes: j=lane&15 (0..14 logits, 15 critic), kc=lane>>4.
__global__ void __launch_bounds__(256) heads_k(
    const float* __restrict__ hseq, const float* __restrict__ aw,
    const float* __restrict__ ab, const float* __restrict__ cw,
    const float* __restrict__ cb, const int* __restrict__ action,
    float* __restrict__ out) {
  const int lane = threadIdx.x & 63;
  const int wid = threadIdx.x >> 6;
  const int row = blockIdx.x * 4 + wid;
  const int j = lane & 15;
  const int kc = lane >> 4;
  const float* f = hseq + (long)row * 512;
  float acc = 0.f;
  if (j < 15) {
    for (int k = kc * 128; k < kc * 128 + 128; ++k) acc += f[k] * aw[k * 15 + j];
  } else {
    for (int k = kc * 128; k < kc * 128 + 128; ++k) acc += f[k] * cw[k];
  }
  acc += __shfl_xor(acc, 16);
  acc += __shfl_xor(acc, 32);
  float logit = (j < 15) ? acc + ab[j] : -1e30f;
  float m = logit;
#pragma unroll
  for (int off = 1; off < 16; off <<= 1) m = fmaxf(m, __shfl_xor(m, off));
  float p = (j < 15) ? expf(logit - m) : 0.f;
  float S = p;
#pragma unroll
  for (int off = 1; off < 16; off <<= 1) S += __shfl_xor(S, off);
  float logS = logf(S);
  float lp = logit - m - logS;
  float e = (j < 15) ? p * lp : 0.f;
  float es = e;
#pragma unroll
  for (int off = 1; off < 16; off <<= 1) es += __shfl_xor(es, off);
  float ent = -es / S;
  int a = action[row];
  float lpa = __shfl(lp, (lane & 48) | a);
  float val = __shfl(acc, (lane & 48) | 15) + cb[0];
  if (lane == 0) {
    out[row] = lpa;
    out[8192 + row] = ent;
    out[16384 + row] = val;
  }
}

// ---------------------------------------------------------------- host ------
extern "C" void kernel_launch(void* const* d_in, const int* in_sizes, int n_in,
                              void* d_out, int out_size, void* d_ws, size_t ws_size,
                              hipStream_t stream) {
  const float* x    = (const float*)d_in[0];
  const float* done = (const float*)d_in[1];
  const float* h0   = (const float*)d_in[2];
  const float* c0   = (const float*)d_in[3];
  const int*   act  = (const int*)d_in[4];
  const float* w1   = (const float*)d_in[5];
  const float* b1   = (const float*)d_in[6];
  const float* w2   = (const float*)d_in[7];
  const float* b2   = (const float*)d_in[8];
  const float* w3   = (const float*)d_in[9];
  const float* b3   = (const float*)d_in[10];
  const float* fcw  = (const float*)d_in[11];
  const float* fcb  = (const float*)d_in[12];
  const float* wih  = (const float*)d_in[13];
  const float* whh  = (const float*)d_in[14];
  const float* blst = (const float*)d_in[15];
  const float* aw   = (const float*)d_in[16];
  const float* ab   = (const float*)d_in[17];
  const float* cw   = (const float*)d_in[18];
  const float* cb   = (const float*)d_in[19];
  float* ws  = (float*)d_ws;
  float* out = (float*)d_out;

  // ws layout (floats); a3/hid/hseq reuse a1's region after a1 is dead.
  float* a1   = ws;                  // 37748736
  float* a3   = ws;                  //  4718592 (reuses a1)
  float* hid  = ws + 4718592;        //  4194304 (reuses a1)
  float* hseq = ws + 8912896;        //  4194304 (reuses a1)
  float* a2   = ws + 37748736;       // 13107200
  float* gxb  = ws + 50855936;       // 16777216
  float* w1t  = ws + 67633152;       //     6144
  float* w2t  = ws + 67639296;       //    32768
  float* w3t  = ws + 67672064;       //    36864
  float* fcwp = ws + 67708928;       //   294912
  float* whhT = ws + 68003840;       //  1048576
  float* hT2  = ws + 69052416;       //    65536 (double-buffered [2][512][64])
  float* cbuf = ws + 69117952;       //    32768  -> total 69150720 f = 277 MB

  hipLaunchKernelGGL(prep_k, dim3(5800), dim3(256), 0, stream,
                     w1, w2, w3, fcw, whh, done, h0, c0,
                     w1t, w2t, w3t, fcwp, whhT, hT2, cbuf);
  hipLaunchKernelGGL(conv1_k, dim3(8192), dim3(256), 0, stream, x, w1t, b1, a1);
  hipLaunchKernelGGL(conv2_k, dim3(4096), dim3(256), 0, stream, a1, w2t, b2, a2);
  hipLaunchKernelGGL(conv3_k, dim3(2048), dim3(256), 0, stream, a2, w3t, b3, a3);
  hipLaunchKernelGGL(gemm_k, dim3(128, 8), dim3(256), 0, stream,
                     a3, fcwp, fcb, hid, 576, 512, 0, 1);
  hipLaunchKernelGGL(gemm_k, dim3(128, 32), dim3(256), 0, stream,
                     hid, wih, blst, gxb, 512, 2048, 1, 0);
  for (int t = 0; t < 128; ++t) {
    hipLaunchKernelGGL(lstm_step_k, dim3(256), dim3(256), 0, stream,
                       gxb, whhT, done, hT2, cbuf, hseq,
                       out + 24576, out + 57344, t);
  }
  hipLaunchKernelGGL(heads_k, dim3(2048), dim3(256), 0, stream,
                     hseq, aw, ab, cw, cb, act, out);
}